// Round 1
// baseline (1176.967 us; speedup 1.0000x reference)
//
#include <hip/hip_runtime.h>
#include <hip/hip_bf16.h>
#include <math.h>

// ---------------------------------------------------------------------------
// GuoCapSAREncoder: conv1(9x9)+ReLU+maxpool2 -> conv2(5x5) -> capsconv(8x8,s2)
// -> squash -> u_hat -> 3x dynamic routing -> likelihood [64,10]
// Round 0: correct fp32 baseline. All convs direct w/ LDS staging; weights
// pre-transposed to [ic][kh][kw][oc] for coalesced loads; u_hat stored as
// [b][t][o][p] so routing reads/writes coalesce over p-lanes.
// ---------------------------------------------------------------------------

#define EPSF 1e-8f

// ---- weight transposes ----------------------------------------------------
__global__ __launch_bounds__(256) void k_t_w2(const float* __restrict__ w2, float* __restrict__ w2T) {
    int i = blockIdx.x * 256 + threadIdx.x;           // 64*128*25 = 204800
    if (i >= 204800) return;
    int oc = i / 3200, rem = i % 3200;                // rem = ic*25 + kh*5 + kw
    w2T[rem * 64 + oc] = w2[i];
}

__global__ __launch_bounds__(256) void k_t_wc(const float* __restrict__ wc, float* __restrict__ wcT) {
    int i = blockIdx.x * 256 + threadIdx.x;           // 128*64*64 = 524288
    if (i >= 524288) return;
    int oc = i / 4096, rem = i % 4096;                // rem = ic*64 + kh*8 + kw
    wcT[rem * 128 + oc] = wc[i];
}

// ---- conv1 9x9 + ReLU + 2x2 maxpool (fused) -------------------------------
// x:[64,1,92,92] w1:[128,1,9,9] -> h1:[64,128,42,42]
__global__ __launch_bounds__(256) void k_conv1_pool(const float* __restrict__ x,
                                                    const float* __restrict__ w1,
                                                    const float* __restrict__ b1,
                                                    float* __restrict__ h1) {
    __shared__ float xs[92 * 92];      // 33.9 KB
    __shared__ float wsh[16 * 81];     // 5.2 KB
    int b = blockIdx.x, ocg = blockIdx.y;   // ocg in [0,8)
    int t = threadIdx.x;
    const float* xb = x + b * 92 * 92;
    for (int j = t; j < 92 * 92; j += 256) xs[j] = xb[j];
    for (int j = t; j < 16 * 81; j += 256) wsh[j] = w1[(ocg * 16) * 81 + j];
    __syncthreads();

    for (int ocl = 0; ocl < 16; ++ocl) {
        int oc = ocg * 16 + ocl;
        float w[81];
#pragma unroll
        for (int k = 0; k < 81; ++k) w[k] = wsh[ocl * 81 + k];  // broadcast reads
        float bias = b1[oc];
        for (int pos = t; pos < 1764; pos += 256) {
            int py = pos / 42, px = pos % 42;
            int iy0 = 2 * py, ix0 = 2 * px;
            float a00 = bias, a01 = bias, a10 = bias, a11 = bias;
#pragma unroll
            for (int r = 0; r < 10; ++r) {      // sliding row window
                float cur[10];
#pragma unroll
                for (int j = 0; j < 10; ++j) cur[j] = xs[(iy0 + r) * 92 + ix0 + j];
                if (r < 9) {
#pragma unroll
                    for (int kw = 0; kw < 9; ++kw) {
                        float wv = w[r * 9 + kw];
                        a00 = fmaf(cur[kw], wv, a00);
                        a01 = fmaf(cur[kw + 1], wv, a01);
                    }
                }
                if (r >= 1) {
#pragma unroll
                    for (int kw = 0; kw < 9; ++kw) {
                        float wv = w[(r - 1) * 9 + kw];
                        a10 = fmaf(cur[kw], wv, a10);
                        a11 = fmaf(cur[kw + 1], wv, a11);
                    }
                }
            }
            float m = fmaxf(fmaxf(a00, a01), fmaxf(a10, a11));
            h1[((b * 128 + oc) * 42 + py) * 42 + px] = fmaxf(m, 0.f);
        }
    }
}

// ---- conv2 5x5 ------------------------------------------------------------
// h1:[64,128,42,42] w2T:[ic*25+khw][64oc] -> h2:[64,64,38,38]
// block = (b, row-pair); thread: oc = t&63, pg = t>>6 -> one row, 19 cols
__global__ __launch_bounds__(256) void k_conv2(const float* __restrict__ h1,
                                               const float* __restrict__ w2T,
                                               const float* __restrict__ b2,
                                               float* __restrict__ h2) {
    __shared__ float ins[32 * 6 * 42];   // 32.3 KB
    int b = blockIdx.x, rp = blockIdx.y;  // rp in [0,19)
    int oh0 = 2 * rp;
    int t = threadIdx.x;
    int oc = t & 63, pg = t >> 6;
    int r0 = pg >> 1, c0 = (pg & 1) * 19;
    int ohr = oh0 + r0;
    float acc[19];
#pragma unroll
    for (int p = 0; p < 19; ++p) acc[p] = 0.f;

    for (int icc = 0; icc < 4; ++icc) {
        int ic0 = icc * 32;
        __syncthreads();
        for (int j = t; j < 8064; j += 256) {
            int icl = j / 252, rem = j % 252;
            int rr = rem / 42, cc = rem % 42;
            ins[j] = h1[((b * 128 + ic0 + icl) * 42 + oh0 + rr) * 42 + cc];
        }
        __syncthreads();
        for (int icl = 0; icl < 32; ++icl) {
            const float* wbase = w2T + (ic0 + icl) * 1600 + oc;
#pragma unroll
            for (int kh = 0; kh < 5; ++kh) {
                float cur[23];
#pragma unroll
                for (int j = 0; j < 23; ++j) cur[j] = ins[icl * 252 + (r0 + kh) * 42 + c0 + j];
#pragma unroll
                for (int kw = 0; kw < 5; ++kw) {
                    float wv = wbase[(kh * 5 + kw) * 64];
#pragma unroll
                    for (int p = 0; p < 19; ++p) acc[p] = fmaf(cur[p + kw], wv, acc[p]);
                }
            }
        }
    }
    float bias = b2[oc];
#pragma unroll
    for (int p = 0; p < 19; ++p)
        h2[((b * 64 + oc) * 38 + ohr) * 38 + c0 + p] = acc[p] + bias;
}

// ---- caps conv 8x8 stride 2 ----------------------------------------------
// h2:[64,64,38,38] wcT:[ic*64+khw][128oc] -> hc:[64,128,16,16]
__global__ __launch_bounds__(256) void k_convcaps(const float* __restrict__ h2,
                                                  const float* __restrict__ wcT,
                                                  const float* __restrict__ bc,
                                                  float* __restrict__ hc) {
    __shared__ float ins[16 * 8 * 38];   // 19.5 KB
    int b = blockIdx.x, oh = blockIdx.y;  // oh in [0,16)
    int t = threadIdx.x;
    int oc = t & 127, half = t >> 7;
    int c0 = half * 8;
    float acc[8];
#pragma unroll
    for (int p = 0; p < 8; ++p) acc[p] = 0.f;

    for (int icc = 0; icc < 4; ++icc) {
        int ic0 = icc * 16;
        __syncthreads();
        for (int j = t; j < 4864; j += 256) {
            int icl = j / 304, rem = j % 304;
            int rr = rem / 38, cc = rem % 38;
            ins[j] = h2[((b * 64 + ic0 + icl) * 38 + 2 * oh + rr) * 38 + cc];
        }
        __syncthreads();
        for (int icl = 0; icl < 16; ++icl) {
            const float* wbase = wcT + (ic0 + icl) * 8192 + oc;
#pragma unroll
            for (int kh = 0; kh < 8; ++kh) {
                float cur[22];
#pragma unroll
                for (int j = 0; j < 22; ++j) cur[j] = ins[icl * 304 + kh * 38 + 2 * c0 + j];
#pragma unroll
                for (int kw = 0; kw < 8; ++kw) {
                    float wv = wbase[(kh * 8 + kw) * 128];
#pragma unroll
                    for (int p = 0; p < 8; ++p) acc[p] = fmaf(cur[2 * p + kw], wv, acc[p]);
                }
            }
        }
    }
    float bias = bc[oc];
#pragma unroll
    for (int p = 0; p < 8; ++p)
        hc[((b * 128 + oc) * 16 + oh) * 16 + c0 + p] = acc[p] + bias;
}

// ---- primary-capsule reorder + squash ------------------------------------
// hc:[64,128,16,16] -> u:[64,1024,32];  p = ct*256 + y*16 + x, ch = ct*32+i
__global__ __launch_bounds__(256) void k_squash(const float* __restrict__ hc,
                                                float* __restrict__ u) {
    int b = blockIdx.x, capg = blockIdx.y;    // capg in [0,128)
    int t = threadIdx.x;
    int capl = t >> 5, i = t & 31;
    int cap = capg * 8 + capl;
    int ct = cap >> 8, rem = cap & 255;       // rem = y*16+x
    float val = hc[(b * 128 + ct * 32 + i) * 256 + rem];
    float s = val * val;
#pragma unroll
    for (int off = 1; off < 32; off <<= 1) s += __shfl_xor(s, off, 64);
    float scale = (s / (1.f + s)) / sqrtf(s + EPSF);
    u[(b * 1024 + cap) * 32 + i] = val * scale;
}

// ---- u_hat -----------------------------------------------------------------
// u:[64,1024,32] Wr:[1024,10,16,32] -> uhT:[b][t][o][p]  (p-coalesced)
__global__ __launch_bounds__(256) void k_uhat(const float* __restrict__ u,
                                              const float* __restrict__ Wr,
                                              float* __restrict__ uhT) {
    int pt = blockIdx.x;   // 16 tiles of 64 p
    int ts = blockIdx.y;   // 10
    int bz = blockIdx.z;   // 4 groups of 16 b
    int t = threadIdx.x;
    int p = pt * 64 + (t & 63);
    int q = t >> 6;
    for (int b = bz * 16 + q; b < bz * 16 + 16; b += 4) {
        float4 uu[8];
        const float4* up = (const float4*)(u + ((size_t)b * 1024 + p) * 32);
#pragma unroll
        for (int j = 0; j < 8; ++j) uu[j] = up[j];
#pragma unroll
        for (int o = 0; o < 16; ++o) {
            const float4* wp = (const float4*)(Wr + (((size_t)p * 10 + ts) * 16 + o) * 32);
            float4 a = {0.f, 0.f, 0.f, 0.f};
#pragma unroll
            for (int j = 0; j < 8; ++j) {
                float4 w4 = wp[j];
                a.x = fmaf(uu[j].x, w4.x, a.x);
                a.y = fmaf(uu[j].y, w4.y, a.y);
                a.z = fmaf(uu[j].z, w4.z, a.z);
                a.w = fmaf(uu[j].w, w4.w, a.w);
            }
            uhT[(((size_t)b * 10 + ts) * 16 + o) * 1024 + p] = (a.x + a.y) + (a.z + a.w);
        }
    }
}

// ---- routing: s = sum_p softmax(bl)_pt * u_hat ; v = squash(s) -------------
// grid (64 b, 10 t). first: bl treated as 0 (c = 0.1). last: writes likelihood.
__global__ __launch_bounds__(256) void k_route_s(const float* __restrict__ uhT,
                                                 const float* __restrict__ bl,
                                                 float* __restrict__ vout,
                                                 float* __restrict__ out,
                                                 int first, int last) {
    __shared__ float sred[4][16];
    int b = blockIdx.x, tt = blockIdx.y;
    int t = threadIdx.x;
    float acc[16];
#pragma unroll
    for (int o = 0; o < 16; ++o) acc[o] = 0.f;
    const float* blb = bl + b * 10240;
    const float* uhb = uhT + ((size_t)b * 10 + tt) * 16384;
    for (int p = t; p < 1024; p += 256) {
        float c;
        if (first) {
            c = 0.1f;
        } else {
            float den = 0.f, et = 0.f;
#pragma unroll
            for (int tp = 0; tp < 10; ++tp) {
                float e = expf(blb[tp * 1024 + p]);
                den += e;
                if (tp == tt) et = e;
            }
            c = et / den;
        }
#pragma unroll
        for (int o = 0; o < 16; ++o)
            acc[o] = fmaf(c, uhb[o * 1024 + p], acc[o]);
    }
    int lane = t & 63, wid = t >> 6;
#pragma unroll
    for (int o = 0; o < 16; ++o) {
        float v = acc[o];
#pragma unroll
        for (int off = 32; off >= 1; off >>= 1) v += __shfl_xor(v, off, 64);
        if (lane == 0) sred[wid][o] = v;
    }
    __syncthreads();
    if (t < 16) {
        float s = (sred[0][t] + sred[1][t]) + (sred[2][t] + sred[3][t]);
        float n2 = s * s;
#pragma unroll
        for (int off = 1; off < 16; off <<= 1) n2 += __shfl_xor(n2, off, 16);
        float scale = (n2 / (1.f + n2)) / sqrtf(n2 + EPSF);
        vout[(b * 10 + tt) * 16 + t] = s * scale;
        if (last && t == 0) {
            float sv2 = n2 * scale * scale;
            out[b * 10 + tt] = sqrtf(sv2 + EPSF);
        }
    }
}

// ---- routing: bl (+)= sum_o u_hat * v -------------------------------------
__global__ __launch_bounds__(256) void k_route_b(const float* __restrict__ uhT,
                                                 const float* __restrict__ vv,
                                                 float* __restrict__ bl,
                                                 int first) {
    __shared__ float vs[16];
    int b = blockIdx.x, tt = blockIdx.y;
    int t = threadIdx.x;
    if (t < 16) vs[t] = vv[(b * 10 + tt) * 16 + t];
    __syncthreads();
    const float* uhb = uhT + ((size_t)b * 10 + tt) * 16384;
    float* blb = bl + (b * 10 + tt) * 1024;
    for (int p = t; p < 1024; p += 256) {
        float d = 0.f;
#pragma unroll
        for (int o = 0; o < 16; ++o) d = fmaf(uhb[o * 1024 + p], vs[o], d);
        blb[p] = first ? d : (blb[p] + d);
    }
}

// ---------------------------------------------------------------------------
extern "C" void kernel_launch(void* const* d_in, const int* in_sizes, int n_in,
                              void* d_out, int out_size, void* d_ws, size_t ws_size,
                              hipStream_t stream) {
    const float* x  = (const float*)d_in[0];
    const float* w1 = (const float*)d_in[1];
    const float* b1 = (const float*)d_in[2];
    const float* w2 = (const float*)d_in[3];
    const float* b2 = (const float*)d_in[4];
    const float* wc = (const float*)d_in[5];
    const float* bc = (const float*)d_in[6];
    const float* Wr = (const float*)d_in[7];
    float* out = (float*)d_out;
    float* ws  = (float*)d_ws;

    // workspace layout (float offsets); uhT overlays h1 (dead after conv2)
    float* w2T = ws;                    // 204800
    float* wcT = ws + 204800;           // 524288
    float* h1  = ws + 729088;           // 14450688
    float* uhT = h1;                    // 10485760 (<= h1 size)
    float* h2  = ws + 15179776;         // 5914624
    float* hc  = ws + 21094400;         // 2097152
    float* u   = ws + 23191552;         // 2097152
    float* bl  = ws + 25288704;         // 655360
    float* vv  = ws + 25944064;         // 10240   -> total ~99 MB

    k_t_w2<<<800, 256, 0, stream>>>(w2, w2T);
    k_t_wc<<<2048, 256, 0, stream>>>(wc, wcT);
    k_conv1_pool<<<dim3(64, 8), 256, 0, stream>>>(x, w1, b1, h1);
    k_conv2<<<dim3(64, 19), 256, 0, stream>>>(h1, w2T, b2, h2);
    k_convcaps<<<dim3(64, 16), 256, 0, stream>>>(h2, wcT, bc, hc);
    k_squash<<<dim3(64, 128), 256, 0, stream>>>(hc, u);
    k_uhat<<<dim3(16, 10, 4), 256, 0, stream>>>(u, Wr, uhT);
    // routing: 3 iterations (b_log starts at 0 -> first pass uses c = 0.1)
    k_route_s<<<dim3(64, 10), 256, 0, stream>>>(uhT, bl, vv, out, 1, 0);
    k_route_b<<<dim3(64, 10), 256, 0, stream>>>(uhT, vv, bl, 1);
    k_route_s<<<dim3(64, 10), 256, 0, stream>>>(uhT, bl, vv, out, 0, 0);
    k_route_b<<<dim3(64, 10), 256, 0, stream>>>(uhT, vv, bl, 0);
    k_route_s<<<dim3(64, 10), 256, 0, stream>>>(uhT, bl, vv, out, 0, 1);
}

// Round 2
// 861.255 us; speedup vs baseline: 1.3666x; 1.3666x over previous
//
#include <hip/hip_runtime.h>
#include <hip/hip_bf16.h>
#include <math.h>

// ---------------------------------------------------------------------------
// GuoCapSAREncoder round 2: bf16-MFMA implicit-GEMM for conv2 + convcaps.
// conv1 emits NHWC bf16; weights pre-transposed to [khw][oc][ic] bf16.
// MFMA 16x16x32_bf16: A row=lane&15,k=quad*8+j ; B col=lane&15,k=quad*8+j ;
// C/D col=lane&15,row=quad*4+reg.
// ---------------------------------------------------------------------------

#define EPSF 1e-8f

typedef __bf16 bf16x8 __attribute__((ext_vector_type(8)));
typedef __bf16 bf16x4 __attribute__((ext_vector_type(4)));
typedef float floatx4 __attribute__((ext_vector_type(4)));

// ---- weight transpose+cast: w2[oc64][ic128][khw25] -> w2b[khw][oc][ic] bf16
__global__ __launch_bounds__(256) void k_t_w2b(const float* __restrict__ w2, __bf16* __restrict__ w2b) {
    int j = blockIdx.x * 256 + threadIdx.x;          // 204800
    if (j >= 204800) return;
    int khw = j / 8192, r2 = j & 8191;
    int oc = r2 >> 7, ic = r2 & 127;
    w2b[j] = (__bf16)w2[(oc * 128 + ic) * 25 + khw];
}

// ---- wc[oc128][ic64][khw64] -> wcb[khw][oc][ic] bf16
__global__ __launch_bounds__(256) void k_t_wcb(const float* __restrict__ wc, __bf16* __restrict__ wcb) {
    int j = blockIdx.x * 256 + threadIdx.x;          // 524288
    if (j >= 524288) return;
    int khw = j / 8192, r2 = j & 8191;
    int oc = r2 >> 6, ic = r2 & 63;
    wcb[j] = (__bf16)wc[(oc * 64 + ic) * 64 + khw];
}

// ---- conv1 9x9 + ReLU + maxpool2 -> h1n NHWC bf16 [b][42][42][128] --------
// lanes = oc (xs reads broadcast); thread does 3 pooled rows x 21 px-pairs
__global__ __launch_bounds__(256, 2) void k_conv1_pool(const float* __restrict__ x,
                                                       const float* __restrict__ w1,
                                                       const float* __restrict__ b1,
                                                       __bf16* __restrict__ h1n) {
    __shared__ float xs[20 * 92];                    // 7.36 KB
    int g = blockIdx.x, b = blockIdx.y;              // g in [0,7)
    int t = threadIdx.x;
    int oc = t & 127, half = t >> 7;
    for (int j = t; j < 1840; j += 256) xs[j] = x[b * 8464 + g * 1104 + j];
    __syncthreads();

    float wr[81];
#pragma unroll
    for (int k = 0; k < 81; ++k) wr[k] = w1[oc * 81 + k];
    float bias = b1[oc];

    for (int pyl = 0; pyl < 3; ++pyl) {
        int py = g * 6 + half * 3 + pyl;
        int lr0 = (half * 3 + pyl) * 2;
        for (int pxp = 0; pxp < 21; ++pxp) {
            int ix0 = 4 * pxp;                       // conv col base
            float a0 = bias, a1 = bias, a2 = bias, a3 = bias;
            float a4 = bias, a5 = bias, a6 = bias, a7 = bias;
#pragma unroll
            for (int r = 0; r < 10; ++r) {
                float cur[12];
                const float2* rp = (const float2*)&xs[(lr0 + r) * 92 + ix0];
#pragma unroll
                for (int j6 = 0; j6 < 6; ++j6) ((float2*)cur)[j6] = rp[j6];
                if (r < 9) {
#pragma unroll
                    for (int kw = 0; kw < 9; ++kw) {
                        float w0 = wr[r * 9 + kw];
                        a0 = fmaf(cur[kw], w0, a0);
                        a1 = fmaf(cur[kw + 1], w0, a1);
                        a2 = fmaf(cur[kw + 2], w0, a2);
                        a3 = fmaf(cur[kw + 3], w0, a3);
                    }
                }
                if (r >= 1) {
#pragma unroll
                    for (int kw = 0; kw < 9; ++kw) {
                        float wv = wr[(r - 1) * 9 + kw];
                        a4 = fmaf(cur[kw], wv, a4);
                        a5 = fmaf(cur[kw + 1], wv, a5);
                        a6 = fmaf(cur[kw + 2], wv, a6);
                        a7 = fmaf(cur[kw + 3], wv, a7);
                    }
                }
            }
            float m0 = fmaxf(fmaxf(a0, a1), fmaxf(a4, a5));
            float m1 = fmaxf(fmaxf(a2, a3), fmaxf(a6, a7));
            int px0 = 2 * pxp;
            size_t base = (((size_t)b * 42 + py) * 42 + px0) * 128 + oc;
            h1n[base] = (__bf16)fmaxf(m0, 0.f);
            h1n[base + 128] = (__bf16)fmaxf(m1, 0.f);
        }
    }
}

// ---- conv2 5x5 via MFMA: h1n NHWC bf16 -> h2n NHWC bf16 [b][38][38][64] ---
// block: 64 oc x 4 output rows (160 pos padded). wave: 2 M-tiles x 5 N-tiles.
__global__ __launch_bounds__(256, 2) void k_conv2(const __bf16* __restrict__ h1n,
                                                  const __bf16* __restrict__ w2b,
                                                  const float* __restrict__ b2,
                                                  __bf16* __restrict__ h2n) {
    __shared__ __bf16 ins[8 * 42 * 64];              // 43008 B
    int g = blockIdx.x, b = blockIdx.y;              // g in [0,10)
    int oh0 = g * 4;
    int t = threadIdx.x;
    int lane = t & 63, w = t >> 6;
    int wm = w & 1, wn = w >> 1;
    int cc = lane & 15, q = lane >> 4;

    int baseN[5], rv[5], cv[5], posv[5];
#pragma unroll
    for (int nt = 0; nt < 5; ++nt) {
        int p = wn * 80 + nt * 16 + cc;
        int pv = p < 152 ? p : 151;
        int r = pv / 38, c = pv - r * 38;
        posv[nt] = p; rv[nt] = r; cv[nt] = c;
        baseN[nt] = (r * 42 + c) * 128 + q * 16;     // bytes (64 ic * 2B)
    }
    floatx4 acc[2][5];
#pragma unroll
    for (int mt = 0; mt < 2; ++mt)
#pragma unroll
        for (int nt = 0; nt < 5; ++nt) acc[mt][nt] = (floatx4){0.f, 0.f, 0.f, 0.f};

    int ocA0 = wm * 32 + cc;
    for (int ic0 = 0; ic0 < 128; ic0 += 64) {
        __syncthreads();
        for (int j = t; j < 2688; j += 256) {        // 8 rows x 42 x 64ic bf16
            int lr = j / 336, rem = j - lr * 336;
            int ix = rem >> 3, icl0 = (rem & 7) * 8;
            int rg = oh0 + lr; if (rg > 41) rg = 41;
            const uint4* src = (const uint4*)(h1n + ((((size_t)b * 42 + rg) * 42 + ix) * 128 + ic0 + icl0));
            *(uint4*)((char*)ins + j * 16) = *src;
        }
        __syncthreads();
#pragma unroll
        for (int khw = 0; khw < 25; ++khw) {
            int kh = khw / 5, kw = khw - kh * 5;
            int boff = (kh * 42 + kw) * 128;
#pragma unroll
            for (int ks = 0; ks < 2; ++ks) {
                bf16x8 a0 = *(const bf16x8*)(w2b + (size_t)(khw * 64 + ocA0) * 128 + ic0 + ks * 32 + q * 8);
                bf16x8 a1 = *(const bf16x8*)(w2b + (size_t)(khw * 64 + ocA0 + 16) * 128 + ic0 + ks * 32 + q * 8);
#pragma unroll
                for (int nt = 0; nt < 5; ++nt) {
                    bf16x8 bfr = *(const bf16x8*)((char*)ins + baseN[nt] + boff + ks * 64);
                    acc[0][nt] = __builtin_amdgcn_mfma_f32_16x16x32_bf16(a0, bfr, acc[0][nt], 0, 0, 0);
                    acc[1][nt] = __builtin_amdgcn_mfma_f32_16x16x32_bf16(a1, bfr, acc[1][nt], 0, 0, 0);
                }
            }
        }
    }
#pragma unroll
    for (int mt = 0; mt < 2; ++mt) {
        int oc0 = wm * 32 + mt * 16 + q * 4;
        float4 bv = *(const float4*)(b2 + oc0);
#pragma unroll
        for (int nt = 0; nt < 5; ++nt) {
            int oh = oh0 + rv[nt];
            if (posv[nt] < 152 && oh < 38) {
                bf16x4 pk;
                pk.x = (__bf16)(acc[mt][nt][0] + bv.x);
                pk.y = (__bf16)(acc[mt][nt][1] + bv.y);
                pk.z = (__bf16)(acc[mt][nt][2] + bv.z);
                pk.w = (__bf16)(acc[mt][nt][3] + bv.w);
                *(bf16x4*)(h2n + ((((size_t)b * 38 + oh) * 38 + cv[nt]) * 64 + oc0)) = pk;
            }
        }
    }
}

// ---- caps conv 8x8 s2 via MFMA: h2n NHWC bf16 -> hcn NHWC fp32 [b][16][16][128]
// block: 128 oc x 4 output rows (64 pos, exact). wave: 2 M-tiles x 4 N-tiles.
__global__ __launch_bounds__(256, 2) void k_convcaps(const __bf16* __restrict__ h2n,
                                                     const __bf16* __restrict__ wcb,
                                                     const float* __restrict__ bc,
                                                     float* __restrict__ hcn) {
    __shared__ __bf16 ins[14 * 38 * 32];             // 34048 B
    int g = blockIdx.x, b = blockIdx.y;              // g in [0,4)
    int oh0 = g * 4;
    int t = threadIdx.x;
    int lane = t & 63, w = t >> 6;
    int cc = lane & 15, q = lane >> 4;

    int baseN[4];
#pragma unroll
    for (int nt = 0; nt < 4; ++nt)
        baseN[nt] = (2 * nt * 38 + 2 * cc) * 64 + q * 16;  // bytes (32 ic * 2B)

    floatx4 acc[2][4];
#pragma unroll
    for (int mt = 0; mt < 2; ++mt)
#pragma unroll
        for (int nt = 0; nt < 4; ++nt) acc[mt][nt] = (floatx4){0.f, 0.f, 0.f, 0.f};

    int ocA = w * 32 + cc;
    for (int ic0 = 0; ic0 < 64; ic0 += 32) {
        __syncthreads();
        for (int j = t; j < 2128; j += 256) {        // 14 rows x 38 x 32ic bf16
            int lr = j / 152, rem = j - lr * 152;
            int ix = rem >> 2, icl0 = (rem & 3) * 8;
            int rg = oh0 * 2 + lr;                   // max 24+13 = 37, in range
            const uint4* src = (const uint4*)(h2n + ((((size_t)b * 38 + rg) * 38 + ix) * 64 + ic0 + icl0));
            *(uint4*)((char*)ins + j * 16) = *src;
        }
        __syncthreads();
#pragma unroll
        for (int khw = 0; khw < 64; ++khw) {
            int kh = khw >> 3, kw = khw & 7;
            int boff = (kh * 38 + kw) * 64;
            bf16x8 a0 = *(const bf16x8*)(wcb + (size_t)(khw * 128 + ocA) * 64 + ic0 + q * 8);
            bf16x8 a1 = *(const bf16x8*)(wcb + (size_t)(khw * 128 + ocA + 16) * 64 + ic0 + q * 8);
#pragma unroll
            for (int nt = 0; nt < 4; ++nt) {
                bf16x8 bfr = *(const bf16x8*)((char*)ins + baseN[nt] + boff);
                acc[0][nt] = __builtin_amdgcn_mfma_f32_16x16x32_bf16(a0, bfr, acc[0][nt], 0, 0, 0);
                acc[1][nt] = __builtin_amdgcn_mfma_f32_16x16x32_bf16(a1, bfr, acc[1][nt], 0, 0, 0);
            }
        }
    }
#pragma unroll
    for (int mt = 0; mt < 2; ++mt) {
        int oc0 = w * 32 + mt * 16 + q * 4;
        float4 bv = *(const float4*)(bc + oc0);
#pragma unroll
        for (int nt = 0; nt < 4; ++nt) {
            int p = nt * 16 + cc;
            int oh = oh0 + (p >> 4), ow = p & 15;
            float4 st;
            st.x = acc[mt][nt][0] + bv.x;
            st.y = acc[mt][nt][1] + bv.y;
            st.z = acc[mt][nt][2] + bv.z;
            st.w = acc[mt][nt][3] + bv.w;
            *(float4*)(hcn + (((size_t)b * 256 + oh * 16 + ow) * 128 + oc0)) = st;
        }
    }
}

// ---- primary-capsule reorder + squash: hcn NHWC -> u:[64,1024,32] ---------
__global__ __launch_bounds__(256) void k_squash(const float* __restrict__ hcn,
                                                float* __restrict__ u) {
    int b = blockIdx.x, capg = blockIdx.y;           // capg in [0,128)
    int t = threadIdx.x;
    int capl = t >> 5, i = t & 31;
    int cap = capg * 8 + capl;
    int ct = cap >> 8, rem = cap & 255;              // rem = y*16+x
    float val = hcn[((size_t)b * 256 + rem) * 128 + ct * 32 + i];
    float s = val * val;
#pragma unroll
    for (int off = 1; off < 32; off <<= 1) s += __shfl_xor(s, off, 64);
    float scale = (s / (1.f + s)) / sqrtf(s + EPSF);
    u[((size_t)b * 1024 + cap) * 32 + i] = val * scale;
}

// ---- u_hat: u:[64,1024,32] Wr:[1024,10,16,32] -> uhT:[b][t][o][p] ---------
__global__ __launch_bounds__(256) void k_uhat(const float* __restrict__ u,
                                              const float* __restrict__ Wr,
                                              float* __restrict__ uhT) {
    int pt = blockIdx.x;   // 16 tiles of 64 p
    int ts = blockIdx.y;   // 10
    int bz = blockIdx.z;   // 4 groups of 16 b
    int t = threadIdx.x;
    int p = pt * 64 + (t & 63);
    int q = t >> 6;
    for (int b = bz * 16 + q; b < bz * 16 + 16; b += 4) {
        float4 uu[8];
        const float4* up = (const float4*)(u + ((size_t)b * 1024 + p) * 32);
#pragma unroll
        for (int j = 0; j < 8; ++j) uu[j] = up[j];
#pragma unroll
        for (int o = 0; o < 16; ++o) {
            const float4* wp = (const float4*)(Wr + (((size_t)p * 10 + ts) * 16 + o) * 32);
            float4 a = {0.f, 0.f, 0.f, 0.f};
#pragma unroll
            for (int j = 0; j < 8; ++j) {
                float4 w4 = wp[j];
                a.x = fmaf(uu[j].x, w4.x, a.x);
                a.y = fmaf(uu[j].y, w4.y, a.y);
                a.z = fmaf(uu[j].z, w4.z, a.z);
                a.w = fmaf(uu[j].w, w4.w, a.w);
            }
            uhT[(((size_t)b * 10 + ts) * 16 + o) * 1024 + p] = (a.x + a.y) + (a.z + a.w);
        }
    }
}

// ---- routing kernels (unchanged) ------------------------------------------
__global__ __launch_bounds__(256) void k_route_s(const float* __restrict__ uhT,
                                                 const float* __restrict__ bl,
                                                 float* __restrict__ vout,
                                                 float* __restrict__ out,
                                                 int first, int last) {
    __shared__ float sred[4][16];
    int b = blockIdx.x, tt = blockIdx.y;
    int t = threadIdx.x;
    float acc[16];
#pragma unroll
    for (int o = 0; o < 16; ++o) acc[o] = 0.f;
    const float* blb = bl + b * 10240;
    const float* uhb = uhT + ((size_t)b * 10 + tt) * 16384;
    for (int p = t; p < 1024; p += 256) {
        float c;
        if (first) {
            c = 0.1f;
        } else {
            float den = 0.f, et = 0.f;
#pragma unroll
            for (int tp = 0; tp < 10; ++tp) {
                float e = expf(blb[tp * 1024 + p]);
                den += e;
                if (tp == tt) et = e;
            }
            c = et / den;
        }
#pragma unroll
        for (int o = 0; o < 16; ++o)
            acc[o] = fmaf(c, uhb[o * 1024 + p], acc[o]);
    }
    int lane = t & 63, wid = t >> 6;
#pragma unroll
    for (int o = 0; o < 16; ++o) {
        float v = acc[o];
#pragma unroll
        for (int off = 32; off >= 1; off >>= 1) v += __shfl_xor(v, off, 64);
        if (lane == 0) sred[wid][o] = v;
    }
    __syncthreads();
    if (t < 16) {
        float s = (sred[0][t] + sred[1][t]) + (sred[2][t] + sred[3][t]);
        float n2 = s * s;
#pragma unroll
        for (int off = 1; off < 16; off <<= 1) n2 += __shfl_xor(n2, off, 16);
        float scale = (n2 / (1.f + n2)) / sqrtf(n2 + EPSF);
        vout[(b * 10 + tt) * 16 + t] = s * scale;
        if (last && t == 0) {
            float sv2 = n2 * scale * scale;
            out[b * 10 + tt] = sqrtf(sv2 + EPSF);
        }
    }
}

__global__ __launch_bounds__(256) void k_route_b(const float* __restrict__ uhT,
                                                 const float* __restrict__ vv,
                                                 float* __restrict__ bl,
                                                 int first) {
    __shared__ float vs[16];
    int b = blockIdx.x, tt = blockIdx.y;
    int t = threadIdx.x;
    if (t < 16) vs[t] = vv[(b * 10 + tt) * 16 + t];
    __syncthreads();
    const float* uhb = uhT + ((size_t)b * 10 + tt) * 16384;
    float* blb = bl + (b * 10 + tt) * 1024;
    for (int p = t; p < 1024; p += 256) {
        float d = 0.f;
#pragma unroll
        for (int o = 0; o < 16; ++o) d = fmaf(uhb[o * 1024 + p], vs[o], d);
        blb[p] = first ? d : (blb[p] + d);
    }
}

// ---------------------------------------------------------------------------
extern "C" void kernel_launch(void* const* d_in, const int* in_sizes, int n_in,
                              void* d_out, int out_size, void* d_ws, size_t ws_size,
                              hipStream_t stream) {
    const float* x  = (const float*)d_in[0];
    const float* w1 = (const float*)d_in[1];
    const float* b1 = (const float*)d_in[2];
    const float* w2 = (const float*)d_in[3];
    const float* b2 = (const float*)d_in[4];
    const float* wc = (const float*)d_in[5];
    const float* bc = (const float*)d_in[6];
    const float* Wr = (const float*)d_in[7];
    float* out = (float*)d_out;
    float* ws  = (float*)d_ws;

    // workspace layout (float offsets)
    __bf16* w2b = (__bf16*)(ws);                  // 204800 bf16 = 102400 f
    __bf16* wcb = (__bf16*)(ws + 102400);         // 524288 bf16 = 262144 f
    __bf16* h1n = (__bf16*)(ws + 364544);         // 14450688 bf16 = 7225344 f
    __bf16* h2n = (__bf16*)(ws + 7589888);        // 5914624 bf16 = 2957312 f
    float*  hcn = ws + 10547200;                  // 2097152 f
    float*  u   = ws + 12644352;                  // 2097152 f
    float*  bl  = ws + 14741504;                  // 655360 f
    float*  vv  = ws + 15396864;                  // 10240 f -> total 15407104 f (61.6 MB)
    float*  uhT = ws + 364544;                    // overlays h1n+h2n+hcn (dead)

    k_t_w2b<<<800, 256, 0, stream>>>(w2, w2b);
    k_t_wcb<<<2048, 256, 0, stream>>>(wc, wcb);
    k_conv1_pool<<<dim3(7, 64), 256, 0, stream>>>(x, w1, b1, h1n);
    k_conv2<<<dim3(10, 64), 256, 0, stream>>>(h1n, w2b, b2, h2n);
    k_convcaps<<<dim3(4, 64), 256, 0, stream>>>(h2n, wcb, bc, hcn);
    k_squash<<<dim3(64, 128), 256, 0, stream>>>(hcn, u);
    k_uhat<<<dim3(16, 10, 4), 256, 0, stream>>>(u, Wr, uhT);
    k_route_s<<<dim3(64, 10), 256, 0, stream>>>(uhT, bl, vv, out, 1, 0);
    k_route_b<<<dim3(64, 10), 256, 0, stream>>>(uhT, vv, bl, 1);
    k_route_s<<<dim3(64, 10), 256, 0, stream>>>(uhT, bl, vv, out, 0, 0);
    k_route_b<<<dim3(64, 10), 256, 0, stream>>>(uhT, vv, bl, 0);
    k_route_s<<<dim3(64, 10), 256, 0, stream>>>(uhT, bl, vv, out, 0, 1);
}